// Round 1
// baseline (15775.385 us; speedup 1.0000x reference)
//
#include <hip/hip_runtime.h>
#include <math.h>

// ---------------------------------------------------------------------------
// VQ_Codex: wav2vec2-style conv feature extractor + 1x1 fusion + VQ quantize.
// Round 1: full fp32 (correctness baseline; argmin parity with np reference).
// Time lengths: 5500 ->1831 ->915 ->457 ->228 ->113 ->56 ; conv batch = 210.
// ---------------------------------------------------------------------------

__device__ __forceinline__ float gelu_f(float x) {
  // exact GELU: x * 0.5 * (1 + erf(x / sqrt(2)))
  return 0.5f * x * (1.0f + erff(x * 0.70710678118654752440f));
}

// conv0: Cin=1, K=10, stride=3  + per-channel GroupNorm over time + GELU.
// grid: (32 groups of 16 channels, n_count); block 256.
__global__ __launch_bounds__(256)
void k_conv0(const float* __restrict__ x, const float* __restrict__ w0,
             const float* __restrict__ g0, const float* __restrict__ b0,
             float* __restrict__ out) {
  __shared__ float xl[5500];
  __shared__ float ht[1831];
  __shared__ float red[8];
  __shared__ float stat[2];
  const int n = blockIdx.y;
  const int tid = threadIdx.x;
  const float* xn = x + (size_t)n * 5500;
  for (int i = tid; i < 5500; i += 256) xl[i] = xn[i];
  __syncthreads();
  const int co_base = blockIdx.x * 16;
  for (int cc = 0; cc < 16; ++cc) {
    const int co = co_base + cc;
    float wr[10];
#pragma unroll
    for (int k = 0; k < 10; ++k) wr[k] = w0[co * 10 + k];
    float s = 0.f, s2 = 0.f;
    for (int t = tid; t < 1831; t += 256) {
      const float* xp = &xl[3 * t];
      float a = 0.f;
#pragma unroll
      for (int k = 0; k < 10; ++k) a += wr[k] * xp[k];
      ht[t] = a;
      s += a;
      s2 += a * a;
    }
#pragma unroll
    for (int o = 32; o > 0; o >>= 1) {
      s  += __shfl_down(s, o);
      s2 += __shfl_down(s2, o);
    }
    if ((tid & 63) == 0) { red[tid >> 6] = s; red[4 + (tid >> 6)] = s2; }
    __syncthreads();
    if (tid == 0) {
      float ts = red[0] + red[1] + red[2] + red[3];
      float tq = red[4] + red[5] + red[6] + red[7];
      float mean = ts * (1.f / 1831.f);
      float var  = tq * (1.f / 1831.f) - mean * mean;
      stat[0] = mean;
      stat[1] = rsqrtf(var + 1e-5f);
    }
    __syncthreads();
    const float mean = stat[0], rs = stat[1];
    const float ga = g0[co], be = b0[co];
    float* on = out + ((size_t)n * 512 + co) * 1831;
    for (int t = tid; t < 1831; t += 256) {
      float v = (ht[t] - mean) * rs * ga + be;
      on[t] = gelu_f(v);
    }
    __syncthreads();  // protect red/stat reuse next channel
  }
}

// Strided conv (Cin=Cout=512, stride=2, K = 2 or 3) + GELU.
// grid: (ceil(Tout/64), 8, n_count); block 256 = 16(ty:co) x 16(tx:t).
// Each thread computes a 4co x 4t micro-tile.
template <int KK>
__global__ __launch_bounds__(256)
void k_conv(const float* __restrict__ in, const float* __restrict__ w,
            float* __restrict__ out, int Tin, int Tout) {
  __shared__ float lw[8][KK][64];   // [ci_l][k][co_l]
  __shared__ float li[8][2][68];    // [ci_l][parity][q]  (q = input_pos>>1 local)
  const int n = blockIdx.z;
  const int co0 = blockIdx.y * 64;
  const int t0 = blockIdx.x * 64;
  const int tid = threadIdx.x;
  const int ty = tid >> 4;   // 0..15 -> co sub-tile
  const int tx = tid & 15;   // 0..15 -> t  sub-tile
  const float* inn = in + (size_t)n * 512 * Tin;
  float acc[4][4] = {};
  const int P = 128 + KK - 1;   // input positions needed per ci row

  for (int ci0 = 0; ci0 < 512; ci0 += 8) {
    __syncthreads();
    // stage weights: co fastest-contiguous in LDS for float4 reads over co
    for (int idx = tid; idx < 8 * KK * 64; idx += 256) {
      int k = idx % KK;
      int ci_l = (idx / KK) & 7;
      int co_l = idx / (KK * 8);
      lw[ci_l][k][co_l] = w[((size_t)(co0 + co_l) * 512 + (ci0 + ci_l)) * KK + k];
    }
    // stage inputs de-interleaved by parity so that stride-2 gathers become
    // contiguous float4 reads: global pos = 2*t0 + p -> li[ci][p&1][p>>1]
    for (int idx = tid; idx < 8 * P; idx += 256) {
      int p = idx % P;
      int ci_l = idx / P;
      int gp = 2 * t0 + p;
      float v = (gp < Tin) ? inn[(size_t)(ci0 + ci_l) * Tin + gp] : 0.f;
      li[ci_l][p & 1][p >> 1] = v;
    }
    __syncthreads();
#pragma unroll
    for (int ci = 0; ci < 8; ++ci) {
      float4 A0 = *(const float4*)&li[ci][0][tx * 4];
      float4 A1 = *(const float4*)&li[ci][1][tx * 4];
      float  e  = li[ci][0][tx * 4 + 4];
#pragma unroll
      for (int k = 0; k < KK; ++k) {
        float4 wv = *(const float4*)&lw[ci][k][ty * 4];
        float wa[4] = {wv.x, wv.y, wv.z, wv.w};
        float bv[4];
        if (k == 0)      { bv[0] = A0.x; bv[1] = A0.y; bv[2] = A0.z; bv[3] = A0.w; }
        else if (k == 1) { bv[0] = A1.x; bv[1] = A1.y; bv[2] = A1.z; bv[3] = A1.w; }
        else             { bv[0] = A0.y; bv[1] = A0.z; bv[2] = A0.w; bv[3] = e;    }
#pragma unroll
        for (int i = 0; i < 4; ++i)
#pragma unroll
          for (int j = 0; j < 4; ++j)
            acc[i][j] += wa[i] * bv[j];
      }
    }
  }
  const int t_lim = Tout - t0;
#pragma unroll
  for (int i = 0; i < 4; ++i) {
    const int co = co0 + ty * 4 + i;
    float* on = out + ((size_t)n * 512 + co) * Tout + t0;
#pragma unroll
    for (int j = 0; j < 4; ++j) {
      const int tt = tx * 4 + j;
      if (tt < t_lim) on[tt] = gelu_f(acc[i][j]);
    }
  }
}

// fusion: z_e[b,d,t] = sum_c h5[(b*105+c),d,t] * fw[c] + fb   (57344 outputs)
__global__ __launch_bounds__(256)
void k_fusion(const float* __restrict__ h5, const float* __restrict__ fw,
              const float* __restrict__ fb, float* __restrict__ ze) {
  const int i = blockIdx.x * 256 + threadIdx.x;   // < 57344 = 2*512*56
  const int b = i / 28672;
  const int r = i % 28672;   // d*56 + t
  float acc = fb[0];
  const float* p = h5 + (size_t)b * 105 * 28672 + r;
  for (int c = 0; c < 105; ++c) acc += p[(size_t)c * 28672] * fw[c];
  ze[i] = acc;
}

// quantize: per (b,t) row, argmin_k |c_k|^2 - 2 z.c_k ; write codebook row to
// z_q and emb. grid (56, 2), block 256 (4 waves; lanes split over D).
__global__ __launch_bounds__(256)
void k_quant(const float* __restrict__ ze, const float* __restrict__ cb,
             float* __restrict__ zq, float* __restrict__ emb) {
  __shared__ float zl[512];
  __shared__ float bw[4];
  __shared__ int bki[4];
  __shared__ int fin;
  const int t = blockIdx.x, b = blockIdx.y;
  const int tid = threadIdx.x;
  for (int d = tid; d < 512; d += 256) zl[d] = ze[((size_t)b * 512 + d) * 56 + t];
  __syncthreads();
  const int wid = tid >> 6, lane = tid & 63;
  const float4 z0 = *(const float4*)&zl[lane * 8];
  const float4 z1 = *(const float4*)&zl[lane * 8 + 4];
  float best = 3.4e38f;
  int bestk = 1 << 30;
  for (int k = wid; k < 1014; k += 4) {
    const float* cr = cb + (size_t)k * 512 + lane * 8;
    const float4 c0 = *(const float4*)cr;
    const float4 c1 = *(const float4*)(cr + 4);
    float cc = c0.x * c0.x + c0.y * c0.y + c0.z * c0.z + c0.w * c0.w
             + c1.x * c1.x + c1.y * c1.y + c1.z * c1.z + c1.w * c1.w;
    float dz = c0.x * z0.x + c0.y * z0.y + c0.z * z0.z + c0.w * z0.w
             + c1.x * z1.x + c1.y * z1.y + c1.z * z1.z + c1.w * z1.w;
    float v = cc - 2.f * dz;
#pragma unroll
    for (int o = 32; o > 0; o >>= 1) v += __shfl_xor(v, o);
    if (v < best) { best = v; bestk = k; }   // ascending k => first-min kept
  }
  if (lane == 0) { bw[wid] = best; bki[wid] = bestk; }
  __syncthreads();
  if (tid == 0) {
    float fv = bw[0];
    int fk = bki[0];
    for (int wq = 1; wq < 4; ++wq)
      if (bw[wq] < fv || (bw[wq] == fv && bki[wq] < fk)) { fv = bw[wq]; fk = bki[wq]; }
    fin = fk;
  }
  __syncthreads();
  const int fk = fin;
  for (int d = tid; d < 512; d += 256) {
    const float v = cb[(size_t)fk * 512 + d];
    const size_t o = ((size_t)b * 512 + d) * 56 + t;
    zq[o] = v;
    emb[o] = v;
  }
}

extern "C" void kernel_launch(void* const* d_in, const int* in_sizes, int n_in,
                              void* d_out, int out_size, void* d_ws, size_t ws_size,
                              hipStream_t stream) {
  const float* x  = (const float*)d_in[0];
  // d_in[1..3]: masks / target ids — unused by the reference computation.
  const float* W0 = (const float*)d_in[4];
  const float* g0 = (const float*)d_in[5];
  const float* b0 = (const float*)d_in[6];
  const float* Wc[5] = {(const float*)d_in[7], (const float*)d_in[8],
                        (const float*)d_in[9], (const float*)d_in[10],
                        (const float*)d_in[11]};
  const float* fw = (const float*)d_in[12];
  const float* fb = (const float*)d_in[13];
  const float* cb = (const float*)d_in[14];
  float* out = (float*)d_out;

  // workspace layout: [h5_full fp32 (210*512*56)] [bufA (NC*512*1831)] [bufB (NC*512*915)]
  char* ws = (char*)d_ws;
  float* h5 = (float*)ws;
  const size_t persist = (size_t)210 * 512 * 56 * sizeof(float);  // 24,084,480 B
  const size_t perA = (size_t)512 * 1831 * sizeof(float);
  const size_t perB = (size_t)512 * 915 * sizeof(float);
  const size_t per_n = perA + perB;                               // 5,623,808 B
  const size_t avail = ws_size > persist ? ws_size - persist : 0;
  long ncl = (long)(avail / per_n);
  int NC = ncl < 1 ? 1 : (ncl > 210 ? 210 : (int)ncl);
  float* bufA = (float*)(ws + persist);
  float* bufB = (float*)(ws + persist + (size_t)NC * perA);

  for (int n0 = 0; n0 < 210; n0 += NC) {
    const int nc = (210 - n0 < NC) ? (210 - n0) : NC;
    k_conv0<<<dim3(32, nc), 256, 0, stream>>>(x + (size_t)n0 * 5500, W0, g0, b0, bufA);
    k_conv<3><<<dim3(15, 8, nc), 256, 0, stream>>>(bufA, Wc[0], bufB, 1831, 915);
    k_conv<3><<<dim3(8, 8, nc), 256, 0, stream>>>(bufB, Wc[1], bufA, 915, 457);
    k_conv<3><<<dim3(4, 8, nc), 256, 0, stream>>>(bufA, Wc[2], bufB, 457, 228);
    k_conv<3><<<dim3(2, 8, nc), 256, 0, stream>>>(bufB, Wc[3], bufA, 228, 113);
    k_conv<2><<<dim3(1, 8, nc), 256, 0, stream>>>(bufA, Wc[4],
                                                  h5 + (size_t)n0 * 512 * 56, 113, 56);
  }
  // z_e -> out[57344:114688]; quantize reads it back, writes z_q and emb.
  k_fusion<<<224, 256, 0, stream>>>(h5, fw, fb, out + 57344);
  k_quant<<<dim3(56, 2), 256, 0, stream>>>(out + 57344, cb, out, out + 114688);
}

// Round 2
// 4789.341 us; speedup vs baseline: 3.2939x; 3.2939x over previous
//
#include <hip/hip_runtime.h>
#include <math.h>

// ---------------------------------------------------------------------------
// VQ_Codex round 2: split-bf16 (hi+lo) implicit-GEMM conv stack on MFMA.
// Numerics: each value v = hi + lo (two bf16); products use 3 MFMAs
// (al*bh + ah*bl + ah*bh) with fp32 accumulation -> ~1e-5 rel error,
// safe for the VQ argmin (gaps ~14, perturbation ~2e-3).
// Layouts: activations [img][t][512c] as separate hi/lo bf16 buffers;
// weights prepped to [k][co][ci] hi/lo bf16; conv5 -> fp32 [img][t][512d].
// ---------------------------------------------------------------------------

typedef __attribute__((ext_vector_type(8))) __bf16 bf16x8;
typedef __attribute__((ext_vector_type(16))) float f32x16;

union U4 { ushort4 v; __bf16 b[4]; };

__device__ __forceinline__ float gelu_f(float x) {
  return 0.5f * x * (1.0f + erff(x * 0.70710678118654752440f));
}

__device__ __forceinline__ void gl_lds16(const __bf16* g, __bf16* l) {
  __builtin_amdgcn_global_load_lds(
      (const __attribute__((address_space(1))) void*)g,
      (__attribute__((address_space(3))) void*)l, 16, 0, 0);
}

// --- weight prep: W fp32 [co][ci][k] -> hi/lo bf16 [k][co][ci] --------------
__global__ __launch_bounds__(256)
void k_wprep(const float* __restrict__ W, __bf16* __restrict__ oh,
             __bf16* __restrict__ ol, int KK, int total) {
  int i = blockIdx.x * 256 + threadIdx.x;
  if (i >= total) return;
  int ci = i & 511, co = (i >> 9) & 511, k = i >> 18;
  float v = W[(co * 512 + ci) * KK + k];
  __bf16 h = (__bf16)v;
  oh[i] = h;
  ol[i] = (__bf16)(v - (float)h);
}

// --- conv0 (Cin=1,K=10,s=3) + GroupNorm + GELU, emits hi/lo [t][c] ---------
__global__ __launch_bounds__(256)
void k_conv0f(const float* __restrict__ x, const float* __restrict__ w0,
              const float* __restrict__ g0, const float* __restrict__ b0,
              __bf16* __restrict__ oHi, __bf16* __restrict__ oLo,
              size_t oStride) {
  __shared__ float xl[5500];
  __shared__ __bf16 hiL[16 * 1831];
  __shared__ __bf16 loL[16 * 1831];
  __shared__ float red[8];
  __shared__ float stat[2];
  const int n = blockIdx.y;
  const int tid = threadIdx.x;
  const float* xn = x + (size_t)n * 5500;
  for (int i = tid; i < 5500; i += 256) xl[i] = xn[i];
  __syncthreads();
  const int co_base = blockIdx.x * 16;
  for (int cc = 0; cc < 16; ++cc) {
    const int co = co_base + cc;
    float wr[10];
#pragma unroll
    for (int k = 0; k < 10; ++k) wr[k] = w0[co * 10 + k];
    float s = 0.f, s2 = 0.f;
    for (int t = tid; t < 1831; t += 256) {
      const float* xp = &xl[3 * t];
      float a = 0.f;
#pragma unroll
      for (int k = 0; k < 10; ++k) a += wr[k] * xp[k];
      s += a;
      s2 += a * a;
    }
#pragma unroll
    for (int o = 32; o > 0; o >>= 1) {
      s += __shfl_down(s, o);
      s2 += __shfl_down(s2, o);
    }
    if ((tid & 63) == 0) { red[tid >> 6] = s; red[4 + (tid >> 6)] = s2; }
    __syncthreads();
    if (tid == 0) {
      float ts = red[0] + red[1] + red[2] + red[3];
      float tq = red[4] + red[5] + red[6] + red[7];
      float mean = ts * (1.f / 1831.f);
      float var = tq * (1.f / 1831.f) - mean * mean;
      stat[0] = mean;
      stat[1] = rsqrtf(var + 1e-5f);
    }
    __syncthreads();
    const float mean = stat[0], rs = stat[1];
    const float ga = g0[co], be = b0[co];
    for (int t = tid; t < 1831; t += 256) {
      const float* xp = &xl[3 * t];
      float a = 0.f;
#pragma unroll
      for (int k = 0; k < 10; ++k) a += wr[k] * xp[k];
      float v = gelu_f((a - mean) * rs * ga + be);
      __bf16 h = (__bf16)v;
      hiL[cc * 1831 + t] = h;
      loL[cc * 1831 + t] = (__bf16)(v - (float)h);
    }
    __syncthreads();
  }
  // write [t][c] chunks: 16 channels * 2B = 32B per t per buffer
  for (int t = tid; t < 1831; t += 256) {
    U4 h[4], l[4];
#pragma unroll
    for (int g = 0; g < 4; ++g)
#pragma unroll
      for (int j = 0; j < 4; ++j) {
        h[g].b[j] = hiL[(g * 4 + j) * 1831 + t];
        l[g].b[j] = loL[(g * 4 + j) * 1831 + t];
      }
    ushort4* dh = (ushort4*)(oHi + (size_t)n * oStride + (size_t)t * 512 + co_base);
    ushort4* dl = (ushort4*)(oLo + (size_t)n * oStride + (size_t)t * 512 + co_base);
#pragma unroll
    for (int g = 0; g < 4; ++g) { dh[g] = h[g].v; dl[g] = l[g].v; }
  }
}

// --- split-bf16 MFMA conv: Cin=Cout=512, stride 2, K=KK, + GELU ------------
// tile 128co x 128t (124 t used), BK=32 ci, 4 waves each 64x64 (2x2 of 32x32).
template <int KK, bool FP32OUT>
__global__ __launch_bounds__(256, 2)
void k_mconv(const __bf16* __restrict__ inHi, const __bf16* __restrict__ inLo,
             const __bf16* __restrict__ wHi, const __bf16* __restrict__ wLo,
             __bf16* __restrict__ outHi, __bf16* __restrict__ outLo,
             float* __restrict__ outF,
             int Tin, int Tout, size_t inStride, size_t outStride) {
  __shared__ __align__(16) __bf16 Asm[KK * 128 * 64];  // [k][co][8 units*8 bf16]
  __shared__ __align__(16) __bf16 Bsm[256 * 64];       // [pos][8 units*8 bf16]
  const int tid = threadIdx.x;
  const int wave = tid >> 6, lane = tid & 63;
  const int lm = lane & 31, lq = lane >> 5;
  const int wco = wave & 1, wt = wave >> 1;
  const int t0 = blockIdx.x * 124;
  const int co0 = blockIdx.y * 128;
  const size_t imgIn = (size_t)blockIdx.z * inStride;

  // precompute DMA source pointers (ci0 added per iteration)
  const __bf16* gA[KK * 4];
#pragma unroll
  for (int j = 0; j < KK * 4; ++j) {
    int cid = (wave * KK * 4 + j) * 64 + lane;
    int row = cid >> 3, u = cid & 7;
    int k = row >> 7, col = row & 127;
    int c = u ^ (col & 7);
    const __bf16* base = (c & 4) ? wLo : wHi;
    gA[j] = base + (size_t)k * 262144 + (size_t)(co0 + col) * 512 + (c & 3) * 8;
  }
  const __bf16* gB[8];
#pragma unroll
  for (int j = 0; j < 8; ++j) {
    int cid = (wave * 8 + j) * 64 + lane;
    int row = cid >> 3, u = cid & 7;
    int c = u ^ (row & 7);
    int pg = 2 * t0 + row;
    if (pg > Tin - 1) pg = Tin - 1;  // clamped: feeds only masked outputs
    gB[j] = ((c & 4) ? inLo : inHi) + imgIn + (size_t)pg * 512 + (c & 3) * 8;
  }
  __bf16* lA = Asm + wave * (KK * 4) * 512;
  __bf16* lB = Bsm + wave * 8 * 512;

  f32x16 acc[2][2] = {};

  for (int ci0 = 0; ci0 < 512; ci0 += 32) {
    __syncthreads();
#pragma unroll
    for (int j = 0; j < KK * 4; ++j) gl_lds16(gA[j] + ci0, lA + j * 512);
#pragma unroll
    for (int j = 0; j < 8; ++j) gl_lds16(gB[j] + ci0, lB + j * 512);
    __syncthreads();
#pragma unroll
    for (int ks = 0; ks < 2; ++ks) {
#pragma unroll
      for (int k = 0; k < KK; ++k) {
        const int cA = ks * 2 + lq;
        bf16x8 ah[2], al[2], bh[2], bl[2];
#pragma unroll
        for (int cs = 0; cs < 2; ++cs) {
          int colL = wco * 64 + cs * 32 + lm;
          const __bf16* rp = Asm + (k * 128 + colL) * 64;
          ah[cs] = *(const bf16x8*)(rp + ((cA ^ (colL & 7)) << 3));
          al[cs] = *(const bf16x8*)(rp + (((cA + 4) ^ (colL & 7)) << 3));
        }
#pragma unroll
        for (int ts = 0; ts < 2; ++ts) {
          int pos = 2 * (wt * 64 + ts * 32 + lm) + k;
          if (pos > 255) pos = 255;
          const __bf16* rp = Bsm + pos * 64;
          bh[ts] = *(const bf16x8*)(rp + ((cA ^ (pos & 7)) << 3));
          bl[ts] = *(const bf16x8*)(rp + (((cA + 4) ^ (pos & 7)) << 3));
        }
#pragma unroll
        for (int cs = 0; cs < 2; ++cs)
#pragma unroll
          for (int ts = 0; ts < 2; ++ts) {
            acc[cs][ts] = __builtin_amdgcn_mfma_f32_32x32x16_bf16(
                al[cs], bh[ts], acc[cs][ts], 0, 0, 0);
            acc[cs][ts] = __builtin_amdgcn_mfma_f32_32x32x16_bf16(
                ah[cs], bl[ts], acc[cs][ts], 0, 0, 0);
            acc[cs][ts] = __builtin_amdgcn_mfma_f32_32x32x16_bf16(
                ah[cs], bh[ts], acc[cs][ts], 0, 0, 0);
          }
      }
    }
  }

  // epilogue: gelu, then split-bf16 (or fp32 for conv5) store
#pragma unroll
  for (int cs = 0; cs < 2; ++cs)
#pragma unroll
    for (int ts = 0; ts < 2; ++ts) {
      int t_l = wt * 64 + ts * 32 + lm;
      int t = t0 + t_l;
      if (t_l < 124 && t < Tout) {
#pragma unroll
        for (int rg = 0; rg < 4; ++rg) {
          int cbase = co0 + wco * 64 + cs * 32 + 8 * rg + 4 * lq;
          float v0 = gelu_f(acc[cs][ts][rg * 4 + 0]);
          float v1 = gelu_f(acc[cs][ts][rg * 4 + 1]);
          float v2 = gelu_f(acc[cs][ts][rg * 4 + 2]);
          float v3 = gelu_f(acc[cs][ts][rg * 4 + 3]);
          if constexpr (FP32OUT) {
            float4 fv = make_float4(v0, v1, v2, v3);
            *(float4*)(outF + (size_t)blockIdx.z * outStride +
                       (size_t)t * 512 + cbase) = fv;
          } else {
            U4 hv, lv;
            __bf16 h0 = (__bf16)v0, h1 = (__bf16)v1, h2 = (__bf16)v2,
                   h3 = (__bf16)v3;
            hv.b[0] = h0; hv.b[1] = h1; hv.b[2] = h2; hv.b[3] = h3;
            lv.b[0] = (__bf16)(v0 - (float)h0);
            lv.b[1] = (__bf16)(v1 - (float)h1);
            lv.b[2] = (__bf16)(v2 - (float)h2);
            lv.b[3] = (__bf16)(v3 - (float)h3);
            size_t o = (size_t)blockIdx.z * outStride + (size_t)t * 512 + cbase;
            *(ushort4*)(outHi + o) = hv.v;
            *(ushort4*)(outLo + o) = lv.v;
          }
        }
      }
    }
}

// --- fusion: z_e[b,d,t] = sum_c h5[b*105+c][t][d] * fw[c] + fb -------------
__global__ __launch_bounds__(256)
void k_fusion(const float* __restrict__ h5, const float* __restrict__ fw,
              const float* __restrict__ fb, float* __restrict__ ze) {
  __shared__ float fwl[105];
  const int t = blockIdx.x, b = blockIdx.y;
  const int tid = threadIdx.x;
  if (tid < 105) fwl[tid] = fw[tid];
  __syncthreads();
  const int d0 = tid * 2;
  float a0 = fb[0], a1 = fb[0];
  const float* p = h5 + ((size_t)b * 105 * 56 + t) * 512 + d0;
  for (int c = 0; c < 105; ++c) {
    float2 v = *(const float2*)(p + (size_t)c * 56 * 512);
    a0 += v.x * fwl[c];
    a1 += v.y * fwl[c];
  }
  ze[((size_t)b * 512 + d0) * 56 + t] = a0;
  ze[((size_t)b * 512 + d0 + 1) * 56 + t] = a1;
}

// --- quantize (unchanged from round 1; fp32, argmin parity) ----------------
__global__ __launch_bounds__(256)
void k_quant(const float* __restrict__ ze, const float* __restrict__ cb,
             float* __restrict__ zq, float* __restrict__ emb) {
  __shared__ float zl[512];
  __shared__ float bw[4];
  __shared__ int bki[4];
  __shared__ int fin;
  const int t = blockIdx.x, b = blockIdx.y;
  const int tid = threadIdx.x;
  for (int d = tid; d < 512; d += 256) zl[d] = ze[((size_t)b * 512 + d) * 56 + t];
  __syncthreads();
  const int wid = tid >> 6, lane = tid & 63;
  const float4 z0 = *(const float4*)&zl[lane * 8];
  const float4 z1 = *(const float4*)&zl[lane * 8 + 4];
  float best = 3.4e38f;
  int bestk = 1 << 30;
  for (int k = wid; k < 1014; k += 4) {
    const float* cr = cb + (size_t)k * 512 + lane * 8;
    const float4 c0 = *(const float4*)cr;
    const float4 c1 = *(const float4*)(cr + 4);
    float cc = c0.x * c0.x + c0.y * c0.y + c0.z * c0.z + c0.w * c0.w
             + c1.x * c1.x + c1.y * c1.y + c1.z * c1.z + c1.w * c1.w;
    float dz = c0.x * z0.x + c0.y * z0.y + c0.z * z0.z + c0.w * z0.w
             + c1.x * z1.x + c1.y * z1.y + c1.z * z1.z + c1.w * z1.w;
    float v = cc - 2.f * dz;
#pragma unroll
    for (int o = 32; o > 0; o >>= 1) v += __shfl_xor(v, o);
    if (v < best) { best = v; bestk = k; }
  }
  if (lane == 0) { bw[wid] = best; bki[wid] = bestk; }
  __syncthreads();
  if (tid == 0) {
    float fv = bw[0];
    int fk = bki[0];
    for (int wq = 1; wq < 4; ++wq)
      if (bw[wq] < fv || (bw[wq] == fv && bki[wq] < fk)) { fv = bw[wq]; fk = bki[wq]; }
    fin = fk;
  }
  __syncthreads();
  const int fk = fin;
  for (int d = tid; d < 512; d += 256) {
    const float v = cb[(size_t)fk * 512 + d];
    const size_t o = ((size_t)b * 512 + d) * 56 + t;
    zq[o] = v;
    emb[o] = v;
  }
}

extern "C" void kernel_launch(void* const* d_in, const int* in_sizes, int n_in,
                              void* d_out, int out_size, void* d_ws, size_t ws_size,
                              hipStream_t stream) {
  const float* x  = (const float*)d_in[0];
  const float* W0 = (const float*)d_in[4];
  const float* g0 = (const float*)d_in[5];
  const float* b0 = (const float*)d_in[6];
  const float* Wc[5] = {(const float*)d_in[7], (const float*)d_in[8],
                        (const float*)d_in[9], (const float*)d_in[10],
                        (const float*)d_in[11]};
  const float* fw = (const float*)d_in[12];
  const float* fb = (const float*)d_in[13];
  const float* cb = (const float*)d_in[14];
  float* out = (float*)d_out;

  const int KKs[5] = {3, 3, 3, 3, 2};
  char* p = (char*)d_ws;
  float* h5 = (float*)p;                       // [210][56][512] fp32
  p += (size_t)210 * 56 * 512 * sizeof(float); // 24,084,480
  __bf16 *wh[5], *wl[5];
  for (int l = 0; l < 5; ++l) {
    size_t sz = (size_t)KKs[l] * 262144;
    wh[l] = (__bf16*)p; p += sz * 2;
    wl[l] = (__bf16*)p; p += sz * 2;
  }
  const size_t persist = (size_t)(p - (char*)d_ws);
  const size_t sA = (size_t)1831 * 512;        // elems per img, buf A
  const size_t sB = (size_t)915 * 512;
  const size_t per_img = (sA * 2 + sB * 2) * sizeof(__bf16);
  long ncl = (ws_size > persist) ? (long)((ws_size - persist) / per_img) : 1;
  int NC = ncl < 1 ? 1 : (ncl > 210 ? 210 : (int)ncl);
  __bf16* AHi = (__bf16*)p;
  __bf16* ALo = AHi + (size_t)NC * sA;
  __bf16* BHi = ALo + (size_t)NC * sA;
  __bf16* BLo = BHi + (size_t)NC * sB;

  for (int l = 0; l < 5; ++l) {
    int total = KKs[l] * 262144;
    k_wprep<<<(total + 255) / 256, 256, 0, stream>>>(Wc[l], wh[l], wl[l],
                                                     KKs[l], total);
  }

  for (int n0 = 0; n0 < 210; n0 += NC) {
    const int nc = (210 - n0 < NC) ? (210 - n0) : NC;
    k_conv0f<<<dim3(32, nc), 256, 0, stream>>>(x + (size_t)n0 * 5500, W0, g0,
                                               b0, AHi, ALo, sA);
    k_mconv<3, false><<<dim3(8, 4, nc), 256, 0, stream>>>(
        AHi, ALo, wh[0], wl[0], BHi, BLo, nullptr, 1831, 915, sA, sB);
    k_mconv<3, false><<<dim3(4, 4, nc), 256, 0, stream>>>(
        BHi, BLo, wh[1], wl[1], AHi, ALo, nullptr, 915, 457, sB, sA);
    k_mconv<3, false><<<dim3(2, 4, nc), 256, 0, stream>>>(
        AHi, ALo, wh[2], wl[2], BHi, BLo, nullptr, 457, 228, sA, sB);
    k_mconv<3, false><<<dim3(1, 4, nc), 256, 0, stream>>>(
        BHi, BLo, wh[3], wl[3], AHi, ALo, nullptr, 228, 113, sB, sA);
    k_mconv<2, true><<<dim3(1, 4, nc), 256, 0, stream>>>(
        AHi, ALo, wh[4], wl[4], nullptr, nullptr,
        h5 + (size_t)n0 * 56 * 512, 113, 56, sA, (size_t)56 * 512);
  }
  k_fusion<<<dim3(56, 2), 256, 0, stream>>>(h5, fw, fb, out + 57344);
  k_quant<<<dim3(56, 2), 256, 0, stream>>>(out + 57344, cb, out, out + 114688);
}